// Round 21
// baseline (425.481 us; speedup 1.0000x reference)
//
#include <hip/hip_runtime.h>
#include <hip/hip_bf16.h>

#define LL 3136
#define HH 56
#define WWD 56
#define DMODEL 384
#define DINNER 768
#define NH 12
#define HD 64
#define DSTATE 64
#define CDIM 896
#define DPROJ 1676
#define PSTRIDE 1680           // padded P row stride in ushorts (3360 B, 16B-aligned rows)
#define LNEPS 1e-5f
#define GRP 8
#define GM (GRP * LL)          // 25088 rows per group
#define NCHUNK 14              // KV L-chunks per (bl,h)
#define TLD 40                 // transposed-LDS row stride (ushorts)
#define YLD 776                // z/x LDS row stride (ushorts)

typedef __attribute__((ext_vector_type(8))) _Float16 half8;
typedef __attribute__((ext_vector_type(4))) float f32x4;

__device__ __forceinline__ unsigned short f2h_bits(float f) {
    _Float16 h = (_Float16)f;   // RNE
    return *reinterpret_cast<unsigned short*>(&h);
}
__device__ __forceinline__ float h2f(unsigned short u) {
    _Float16 h = *reinterpret_cast<_Float16*>(&u);
    return (float)h;
}

__device__ __forceinline__ f32x4 mfma16h(half8 a, half8 b, f32x4 c) {
    return __builtin_amdgcn_mfma_f32_16x16x32_f16(a, b, c, 0, 0, 0);
}

// async global->LDS, 16B per lane; dest = lds base (wave-uniform) + lane*16
__device__ __forceinline__ void gload16(const unsigned short* g, unsigned short* l) {
    __builtin_amdgcn_global_load_lds(
        (const __attribute__((address_space(1))) unsigned int*)g,
        (__attribute__((address_space(3))) unsigned int*)l, 16, 0, 0);
}

// elementwise convert fp32 -> fp16 (RNE)
__global__ __launch_bounds__(256) void cvt_f16(
    const float* __restrict__ in, unsigned short* __restrict__ out, int n4)
{
    int i = blockIdx.x * 256 + threadIdx.x;
    if (i >= n4) return;
    float4 v = ((const float4*)in)[i];
    ushort4 o;
    o.x = f2h_bits(v.x); o.y = f2h_bits(v.y);
    o.z = f2h_bits(v.z); o.w = f2h_bits(v.w);
    ((ushort4*)out)[i] = o;
}

// pack conv weights f32 [c][tap] -> fp16 [tap][c]
__global__ __launch_bounds__(256) void pack_w16(
    const float* __restrict__ cw, unsigned short* __restrict__ wt)
{
    int c = blockIdx.x * 256 + threadIdx.x;
    if (c >= CDIM) return;
#pragma unroll
    for (int tap = 0; tap < 9; ++tap)
        wt[tap * CDIM + c] = f2h_bits(cw[c * 9 + tap]);
}

// C[m,n] = sum_k A[m,k]*B[n,k], fp16 operands, fp32 acc; OUT16 selects fp16/fp32 store.
// m97 structure + T1 XCD swizzle + LDS-staged epilogue (8 coalesced 16B stores/thread).
template<int MT, int OUT16>
__global__ __launch_bounds__(256) void gemm_h(
    const unsigned short* __restrict__ Ah, int lda,
    const unsigned short* __restrict__ Bh, int ldb,
    void* __restrict__ Cp, int ldc, int N, int K)
{
    constexpr int BM = MT * 32;
    __shared__ __align__(16) unsigned short smem[16384];   // 32 KB: staging & epilogue alias
    unsigned short* const Ahs = smem;                      // BM*64
    unsigned short* const Bhs = smem + BM * 64;            // 128*64
    const int t = threadIdx.x;
    const int lane = t & 63;
    const int w = t >> 6;

    // XCD-chunked bijective swizzle: same-XCD-consecutive blocks share bm (A-panel L2 reuse)
    const int nbx = gridDim.x;
    const int total = nbx * gridDim.y;
    const int lin = blockIdx.y * nbx + blockIdx.x;
    const int chunk = total >> 3;
    const int newlin = (lin & 7) * chunk + (lin >> 3);
    const int bn = (newlin % nbx) * 128;
    const int bm = (newlin / nbx) * BM;

    const int wr = (w >> 1) * (MT * 16);
    const int wc = (w & 1) * 64;
    const int l15 = lane & 15;
    const int g   = lane >> 4;
    const int srow = lane >> 3;
    const int slot = lane & 7;

    f32x4 acc[MT][4];
#pragma unroll
    for (int m = 0; m < MT; ++m)
#pragma unroll
        for (int n = 0; n < 4; ++n) acc[m][n] = (f32x4){0.f, 0.f, 0.f, 0.f};

    for (int k0 = 0; k0 < K; k0 += 64) {
#pragma unroll
        for (int it = 0; it < MT; ++it) {            // A: BM rows
            int rowblk = w * (8 * MT) + it * 8;
            int row = rowblk + srow;
            int sl = (slot ^ (row & 7)) * 8;
            size_t goff = (size_t)(bm + row) * lda + k0 + sl;
            gload16(Ah + goff, Ahs + rowblk * 64);
        }
#pragma unroll
        for (int it = 0; it < 4; ++it) {             // B: 128 rows
            int rowblk = w * 32 + it * 8;
            int row = rowblk + srow;
            int n = bn + row; if (n > N - 1) n = N - 1;
            int sl = (slot ^ (row & 7)) * 8;
            size_t goff = (size_t)n * ldb + k0 + sl;
            gload16(Bh + goff, Bhs + rowblk * 64);
        }
        __syncthreads();

#pragma unroll
        for (int ks = 0; ks < 2; ++ks) {
            half8 av[MT], bv[4];
#pragma unroll
            for (int m = 0; m < MT; ++m) {
                int arow = wr + m * 16 + l15;
                int off = arow * 64 + (((ks * 4 + g) ^ (arow & 7)) << 3);
                av[m] = *(const half8*)&Ahs[off];
            }
#pragma unroll
            for (int n = 0; n < 4; ++n) {
                int brow = wc + n * 16 + l15;
                int off = brow * 64 + (((ks * 4 + g) ^ (brow & 7)) << 3);
                bv[n] = *(const half8*)&Bhs[off];
            }
#pragma unroll
            for (int m = 0; m < MT; ++m)
#pragma unroll
                for (int n = 0; n < 4; ++n)
                    acc[m][n] = mfma16h(av[m], bv[n], acc[m][n]);
        }
        __syncthreads();   // final iter: LDS free for epilogue reuse
    }

    // ---- epilogue: fragments -> LDS tile, then bulk coalesced stores ----
    if (OUT16) {
        unsigned short* Es = smem;                   // [BM][128] fp16
#pragma unroll
        for (int n = 0; n < 4; ++n)
#pragma unroll
            for (int m = 0; m < MT; ++m)
#pragma unroll
                for (int ri = 0; ri < 4; ++ri) {
                    int row = wr + m * 16 + (g << 2) + ri;
                    int col = wc + n * 16 + l15;
                    Es[row * 128 + col] = f2h_bits(acc[m][n][ri]);
                }
    } else {
        float* Ef = (float*)smem;                    // [BM][128] fp32 (BM=64 fits 32 KB)
#pragma unroll
        for (int n = 0; n < 4; ++n)
#pragma unroll
            for (int m = 0; m < MT; ++m)
#pragma unroll
                for (int ri = 0; ri < 4; ++ri) {
                    int row = wr + m * 16 + (g << 2) + ri;
                    int col = wc + n * 16 + l15;
                    Ef[row * 128 + col] = acc[m][n][ri];
                }
    }
    __syncthreads();

    if (OUT16) {
        unsigned short* Es = smem;
        unsigned short* C = (unsigned short*)Cp;
#pragma unroll
        for (int pass = 0; pass < BM * 16 / 256; ++pass) {
            int idx = pass * 256 + t;
            int row = idx >> 4, col = (idx & 15) * 8;
            int gcol = bn + col;
            if (gcol + 8 <= N) {
                *(half8*)&C[(size_t)(bm + row) * ldc + gcol] = *(const half8*)&Es[row * 128 + col];
            } else {
                for (int j = 0; j < 8; ++j)
                    if (gcol + j < N)
                        C[(size_t)(bm + row) * ldc + gcol + j] = Es[row * 128 + col + j];
            }
        }
    } else {
        float* Ef = (float*)smem;
        float* C = (float*)Cp;
#pragma unroll
        for (int pass = 0; pass < BM * 32 / 256; ++pass) {
            int idx = pass * 256 + t;
            int row = idx >> 5, col = (idx & 31) * 4;
            int gcol = bn + col;
            if (gcol + 4 <= N) {
                *(float4*)&C[(size_t)(bm + row) * ldc + gcol] = *(const float4*)&Ef[row * 128 + col];
            } else {
                for (int j = 0; j < 4; ++j)
                    if (gcol + j < N)
                        C[(size_t)(bm + row) * ldc + gcol + j] = Ef[row * 128 + col + j];
            }
        }
    }
}

// depthwise 3x3 conv (pad 1) + bias + SiLU. 8 channels x 4 w-positions per thread.
// T1 XCD-chunked swizzle: XCD k sweeps batch-image k in l-order -> halo rows stay in its L2.
__global__ __launch_bounds__(128) void conv_silu(
    const unsigned short* __restrict__ P, const unsigned short* __restrict__ wt,
    const float* __restrict__ cb, unsigned short* __restrict__ XC)
{
    const int t = threadIdx.x;
    if (t >= 112) return;
    const int c8 = t * 8;

    // bijective XCD-chunked remap of (bl, l-block)
    const int nbx = gridDim.x;                 // 784
    const int total = nbx * gridDim.y;         // 6272, %8==0
    const int lin = blockIdx.y * nbx + blockIdx.x;
    const int chunk = total >> 3;
    const int newlin = (lin & 7) * chunk + (lin >> 3);
    const int bl = newlin / nbx;
    const int l0 = (newlin % nbx) * 4;         // 4 outputs in one spatial row (56 % 4 == 0)

    const int h = l0 / WWD, w0 = l0 % WWD;

    float acc[4][8];
    float4 b0 = *(const float4*)&cb[c8];
    float4 b1 = *(const float4*)&cb[c8 + 4];
#pragma unroll
    for (int o = 0; o < 4; ++o) {
        acc[o][0] = b0.x; acc[o][1] = b0.y; acc[o][2] = b0.z; acc[o][3] = b0.w;
        acc[o][4] = b1.x; acc[o][5] = b1.y; acc[o][6] = b1.z; acc[o][7] = b1.w;
    }

    const unsigned short* pb = P + (size_t)bl * LL * PSTRIDE + DINNER + c8;

#pragma unroll
    for (int kh = 0; kh < 3; ++kh) {
        int h2 = h + kh - 1;
        bool hok = (unsigned)h2 < HH;
        float xf[6][8];
#pragma unroll
        for (int j = 0; j < 6; ++j) {
            int wj = w0 - 1 + j;
            if (hok && (unsigned)wj < WWD) {
                half8 v = *(const half8*)&pb[(size_t)(h2 * WWD + wj) * PSTRIDE];
#pragma unroll
                for (int q = 0; q < 8; ++q) xf[j][q] = (float)v[q];
            } else {
#pragma unroll
                for (int q = 0; q < 8; ++q) xf[j][q] = 0.f;
            }
        }
#pragma unroll
        for (int kw = 0; kw < 3; ++kw) {
            half8 wv = *(const half8*)&wt[(kh * 3 + kw) * CDIM + c8];
            float wf[8];
#pragma unroll
            for (int q = 0; q < 8; ++q) wf[q] = (float)wv[q];
#pragma unroll
            for (int o = 0; o < 4; ++o)
#pragma unroll
                for (int q = 0; q < 8; ++q)
                    acc[o][q] += wf[q] * xf[o + kw][q];
        }
    }

#pragma unroll
    for (int o = 0; o < 4; ++o) {
        half8 ov;
#pragma unroll
        for (int q = 0; q < 8; ++q) {
            float a = acc[o][q];
            ov[q] = (_Float16)(a / (1.f + __expf(-a)));
        }
        *(half8*)&XC[((size_t)bl * LL + l0 + o) * CDIM + c8] = ov;
    }
}

// KV partial via MFMA: KVpart[chunk][bl,h][p][s] = sum_{l in chunk} Bcf[l,s]*x[l,h*64+p].
// Transposed fp16 LDS staging (BshT[64s][TLD], XshT[64p][TLD]); cf folded into B at staging.
__global__ __launch_bounds__(256) void kv_kernel(
    const unsigned short* __restrict__ XC, const unsigned short* __restrict__ P,
    const float* __restrict__ dt_bias, const float* __restrict__ A_log,
    float* __restrict__ KVpart)
{
    int h  = blockIdx.x;
    int bl = blockIdx.y;
    int lbase = blockIdx.z * 224;
    __shared__ __align__(16) unsigned short BshT[64 * TLD];
    __shared__ __align__(16) unsigned short XshT[64 * TLD];
    const int t = threadIdx.x;
    const int lane = t & 63;
    const int w = t >> 6;
    const int l15 = lane & 15;
    const int kg = lane >> 4;       // k-group 0..3
    const int pw = w * 16;          // wave's p-slab
    const int sl = t & 31;          // staging l row 0..31
    const int c8 = (t >> 5) * 8;    // staging channel group 0..56

    f32x4 acc[4];
#pragma unroll
    for (int sf = 0; sf < 4; ++sf) acc[sf] = (f32x4){0.f, 0.f, 0.f, 0.f};

    const unsigned short* xbase = XC + (size_t)bl * LL * CDIM;
    const unsigned short* pdt = P + (size_t)bl * LL * PSTRIDE + DINNER + CDIM + h;
    const float nA = -__expf(A_log[h]);
    const float db = dt_bias[h];

    // prefetch subtile 0
    ushort4 Bv[2], Xv[2];
    float dtv;
    {
        const unsigned short* r = xbase + (size_t)(lbase + sl) * CDIM;
        Bv[0] = *(const ushort4*)&r[DINNER + c8];
        Bv[1] = *(const ushort4*)&r[DINNER + c8 + 4];
        Xv[0] = *(const ushort4*)&r[h * HD + c8];
        Xv[1] = *(const ushort4*)&r[h * HD + c8 + 4];
        dtv = h2f(pdt[(size_t)(lbase + sl) * PSTRIDE]);
    }

    for (int c = 0; c < 7; ++c) {
        __syncthreads();   // previous compute done; LDS free
        {
            float x = dtv + db;
            float sp = (x > 20.f) ? x : log1pf(__expf(x));
            float cfr = nA * sp;
#pragma unroll
            for (int i = 0; i < 4; ++i) {
                BshT[(c8 + i) * TLD + sl]     = f2h_bits(h2f(((const unsigned short*)&Bv[0])[i]) * cfr);
                BshT[(c8 + 4 + i) * TLD + sl] = f2h_bits(h2f(((const unsigned short*)&Bv[1])[i]) * cfr);
                XshT[(c8 + i) * TLD + sl]     = ((const unsigned short*)&Xv[0])[i];
                XshT[(c8 + 4 + i) * TLD + sl] = ((const unsigned short*)&Xv[1])[i];
            }
        }
        __syncthreads();   // tile ready

        if (c < 6) {       // issue next subtile's loads; land during MFMA
            int lrow = lbase + (c + 1) * 32 + sl;
            const unsigned short* r = xbase + (size_t)lrow * CDIM;
            Bv[0] = *(const ushort4*)&r[DINNER + c8];
            Bv[1] = *(const ushort4*)&r[DINNER + c8 + 4];
            Xv[0] = *(const ushort4*)&r[h * HD + c8];
            Xv[1] = *(const ushort4*)&r[h * HD + c8 + 4];
            dtv = h2f(pdt[(size_t)lrow * PSTRIDE]);
        }

        // MFMA: A = X^T rows (p), B = Bcf^T rows (s), k = 32 l of this subtile
        half8 av = *(const half8*)&XshT[(pw + l15) * TLD + kg * 8];
#pragma unroll
        for (int sf = 0; sf < 4; ++sf) {
            half8 bv = *(const half8*)&BshT[(sf * 16 + l15) * TLD + kg * 8];
            acc[sf] = mfma16h(av, bv, acc[sf]);
        }
    }

    // C/D layout: col(s) = l15, row(p) = kg*4 + ri (within wave's p-slab)
    float* outp = KVpart + ((size_t)blockIdx.z * GRP * NH + (size_t)bl * NH + h) * (HD * DSTATE);
#pragma unroll
    for (int sf = 0; sf < 4; ++sf)
#pragma unroll
        for (int ri = 0; ri < 4; ++ri)
            outp[(size_t)(pw + kg * 4 + ri) * DSTATE + sf * 16 + l15] = acc[sf][ri];
}

// sum NCHUNK partials (fp32, fixed order) -> fp16 KV16
__global__ __launch_bounds__(256) void kv_reduce(
    const float* __restrict__ KVpart, unsigned short* __restrict__ KV16, int n4)
{
    int i = blockIdx.x * 256 + threadIdx.x;
    if (i >= n4) return;
    float4 s = ((const float4*)KVpart)[i];
#pragma unroll
    for (int c = 1; c < NCHUNK; ++c) {
        float4 v = ((const float4*)KVpart)[(size_t)c * n4 + i];
        s.x += v.x; s.y += v.y; s.z += v.z; s.w += v.w;
    }
    ushort4 o;
    o.x = f2h_bits(s.x); o.y = f2h_bits(s.y);
    o.z = f2h_bits(s.z); o.w = f2h_bits(s.w);
    ((ushort4*)KV16)[i] = o;
}

// Fused: yg = (Cmat @ KVcat + x*D) * silu(z); LayerNorm(768); y fp16 -> P z cols.
// LDS-staged: z/x/C tiles coalesced into LDS; gating/LN from LDS; bulk write-back.
__global__ __launch_bounds__(256) void ckv_ln(
    unsigned short* __restrict__ P, const unsigned short* __restrict__ XC,
    const unsigned short* __restrict__ KV16, const float* __restrict__ Dp,
    const float* __restrict__ ln_g, const float* __restrict__ ln_b)
{
    const int t = threadIdx.x;
    const int lane = t & 63;
    const int w = t >> 6;
    const int r0 = blockIdx.x * 16;
    const int bl = blockIdx.y;
    const int l15 = lane & 15;
    const int q4 = lane >> 4;          // row-quarter
    const int dw = w * 192;

    __shared__ float ps1[4][16], ps2[4][16];
    __shared__ __align__(16) unsigned short zs[16][YLD];
    __shared__ __align__(16) unsigned short xs[16][YLD];
    __shared__ __align__(16) unsigned short Cs[16][72];

    const size_t gbase = (size_t)bl * LL + r0;

    // stage z (P cols 0..767), x (XC cols 0..767) coalesced; C tile (cols 832..895)
#pragma unroll
    for (int pass = 0; pass < 6; ++pass) {
        int idx = pass * 256 + t;
        int row = idx / 96, slot = idx % 96;
        *(half8*)&zs[row][slot * 8] = *(const half8*)&P[(gbase + row) * PSTRIDE + slot * 8];
        *(half8*)&xs[row][slot * 8] = *(const half8*)&XC[(gbase + row) * CDIM + slot * 8];
    }
    if (t < 128) {
        int row = t >> 3, slot = t & 7;
        *(half8*)&Cs[row][slot * 8] =
            *(const half8*)&XC[(gbase + row) * CDIM + DINNER + DSTATE + slot * 8];
    }
    __syncthreads();

    f32x4 acc[12];
#pragma unroll
    for (int n = 0; n < 12; ++n) acc[n] = (f32x4){0.f, 0.f, 0.f, 0.f};

    const unsigned short* kvb = KV16 + (size_t)bl * NH * HD * DSTATE;

    float dch[12];
#pragma unroll
    for (int n = 0; n < 12; ++n) dch[n] = Dp[(dw + n * 16) >> 6];

#pragma unroll
    for (int ks = 0; ks < 2; ++ks) {
        int koff = ks * 32 + q4 * 8;
        half8 av = *(const half8*)&Cs[l15][koff];
#pragma unroll
        for (int n = 0; n < 12; ++n) {
            int d = dw + n * 16 + l15;
            int hh = d >> 6, p = d & 63;
            half8 bv = *(const half8*)&kvb[((size_t)hh * HD + p) * DSTATE + koff];
            acc[n] = mfma16h(av, bv, acc[n]);
        }
    }

    // gate from LDS + per-row partial sums
    float s1[4], s2[4];
#pragma unroll
    for (int ri = 0; ri < 4; ++ri) {
        int rloc = q4 * 4 + ri;
        float a1 = 0.f, a2 = 0.f;
#pragma unroll
        for (int n = 0; n < 12; ++n) {
            int d = dw + n * 16 + l15;
            float x = h2f(xs[rloc][d]);
            float z = h2f(zs[rloc][d]);
            float sz = z / (1.f + __expf(-z));
            float yg = (acc[n][ri] + x * dch[n]) * sz;
            acc[n][ri] = yg;
            a1 += yg; a2 += yg * yg;
        }
#pragma unroll
        for (int off = 1; off < 16; off <<= 1) {
            a1 += __shfl_xor(a1, off);
            a2 += __shfl_xor(a2, off);
        }
        s1[ri] = a1; s2[ri] = a2;
    }
    if (l15 == 0) {
#pragma unroll
        for (int ri = 0; ri < 4; ++ri) {
            ps1[w][q4 * 4 + ri] = s1[ri];
            ps2[w][q4 * 4 + ri] = s2[ri];
        }
    }
    __syncthreads();

    // per-lane gamma/beta for its 12 columns
    float gg[12], bb2[12];
#pragma unroll
    for (int n = 0; n < 12; ++n) {
        int d = dw + n * 16 + l15;
        gg[n] = ln_g[d];
        bb2[n] = ln_b[d];
    }

#pragma unroll
    for (int ri = 0; ri < 4; ++ri) {
        int rloc = q4 * 4 + ri;
        float S1 = ps1[0][rloc] + ps1[1][rloc] + ps1[2][rloc] + ps1[3][rloc];
        float S2 = ps2[0][rloc] + ps2[1][rloc] + ps2[2][rloc] + ps2[3][rloc];
        float mu = S1 * (1.f / 768.f);
        float var = S2 * (1.f / 768.f) - mu * mu;
        float rstd = rsqrtf(var + LNEPS);
#pragma unroll
        for (int n = 0; n < 12; ++n) {
            int d = dw + n * 16 + l15;
            zs[rloc][d] = f2h_bits((acc[n][ri] - mu) * rstd * gg[n] + bb2[n]);
        }
    }
    __syncthreads();

    // bulk coalesced write-back of y into P z cols
#pragma unroll
    for (int pass = 0; pass < 6; ++pass) {
        int idx = pass * 256 + t;
        int row = idx / 96, slot = idx % 96;
        *(half8*)&P[(gbase + row) * PSTRIDE + slot * 8] = *(const half8*)&zs[row][slot * 8];
    }
}

extern "C" void kernel_launch(void* const* d_in, const int* in_sizes, int n_in,
                              void* d_out, int out_size, void* d_ws, size_t ws_size,
                              hipStream_t stream)
{
    const float* u       = (const float*)d_in[0];
    const float* W_in    = (const float*)d_in[1];
    const float* conv_w  = (const float*)d_in[2];
    const float* conv_b  = (const float*)d_in[3];
    const float* dt_bias = (const float*)d_in[4];
    const float* A_log   = (const float*)d_in[5];
    const float* Dp      = (const float*)d_in[6];
    const float* ln_g    = (const float*)d_in[7];
    const float* ln_b    = (const float*)d_in[8];
    const float* W_out   = (const float*)d_in[9];
    float* out = (float*)d_out;
    (void)ws_size;

    const int B = in_sizes[0] / (LL * DMODEL);   // 16
    const int M = B * LL;                        // 50176

    const size_t kvsz = (size_t)GRP * NH * HD * DSTATE;     // 393216

    // workspace (~192 MiB)
    unsigned short* P  = (unsigned short*)d_ws;             // GM*PSTRIDE fp16
    unsigned short* XC = P + (size_t)GM * PSTRIDE;          // GM*896 fp16
    float* KVpart = (float*)(XC + (size_t)GM * CDIM);       // NCHUNK*kvsz f32 (~22 MB)
    unsigned short* KV16 = (unsigned short*)(KVpart + (size_t)NCHUNK * kvsz);
    unsigned short* u16  = KV16 + kvsz;                     // M*384
    unsigned short* Wi16 = u16 + (size_t)M * DMODEL;        // 1676*384
    unsigned short* Wo16 = Wi16 + (size_t)DPROJ * DMODEL;   // 384*768
    unsigned short* wt16 = Wo16 + (size_t)DMODEL * DINNER;  // 9*896

    // one-time fp16 converts / packs
    cvt_f16<<<((size_t)M * DMODEL / 4 + 255) / 256, 256, 0, stream>>>(u, u16, M * DMODEL / 4);
    cvt_f16<<<(DPROJ * DMODEL / 4 + 255) / 256, 256, 0, stream>>>(W_in, Wi16, DPROJ * DMODEL / 4);
    cvt_f16<<<(DMODEL * DINNER / 4 + 255) / 256, 256, 0, stream>>>(W_out, Wo16, DMODEL * DINNER / 4);
    pack_w16<<<(CDIM + 255) / 256, 256, 0, stream>>>(conv_w, wt16);

    const int nkv4 = (int)(kvsz / 4);

    for (int b0 = 0; b0 < B; b0 += GRP) {
        // 1) P = u_grp @ W_in^T  (fp16 MFMA, fp16 store; grid 14x196=2744, %8==0, XCD-swizzled)
        gemm_h<4, 1><<<dim3(14, GM / 128), 256, 0, stream>>>(
            u16 + (size_t)b0 * LL * DMODEL, DMODEL, Wi16, DMODEL, P, PSTRIDE, DPROJ, DMODEL);

        // 2) depthwise conv + SiLU (8ch x 4w per thread; grid 784x8=6272, %8==0, XCD-swizzled)
        conv_silu<<<dim3(LL / 4, GRP), 128, 0, stream>>>(P, wt16, conv_b, XC);

        // 3) KV partials via MFMA (transposed fp16 staging, cf folded into B)
        kv_kernel<<<dim3(NH, GRP, NCHUNK), 256, 0, stream>>>(XC, P, dt_bias, A_log, KVpart);

        // 4) reduce partials -> fp16 KV16
        kv_reduce<<<(nkv4 + 255) / 256, 256, 0, stream>>>(KVpart, KV16, nkv4);

        // 5) fused yg = (C@KV + x*D)*silu(z) + LayerNorm -> y fp16 into P z cols (LDS-staged)
        ckv_ln<<<dim3(LL / 16, GRP), 256, 0, stream>>>(P, XC, KV16, Dp, ln_g, ln_b);

        // 6) out_grp = y @ W_out^T  (fp16 A in P, fp32 out; grid 3x392=1176, %8==0, swizzled)
        gemm_h<2, 0><<<dim3(3, GM / 64), 256, 0, stream>>>(
            P, PSTRIDE, Wo16, DINNER,
            out + (size_t)b0 * LL * DMODEL, DMODEL, DMODEL, DINNER);
    }
}

// Round 22
// 418.773 us; speedup vs baseline: 1.0160x; 1.0160x over previous
//
#include <hip/hip_runtime.h>
#include <hip/hip_bf16.h>

#define LL 3136
#define HH 56
#define WWD 56
#define DMODEL 384
#define DINNER 768
#define NH 12
#define HD 64
#define DSTATE 64
#define CDIM 896
#define DPROJ 1676
#define PSTRIDE 1680           // padded P row stride in ushorts (3360 B, 16B-aligned rows)
#define LNEPS 1e-5f
#define NCHUNK 14              // KV L-chunks per (bl,h)
#define TLD 40                 // transposed-LDS row stride (ushorts)
#define YLD 776                // z/x LDS row stride (ushorts)

typedef __attribute__((ext_vector_type(8))) _Float16 half8;
typedef __attribute__((ext_vector_type(4))) float f32x4;

__device__ __forceinline__ unsigned short f2h_bits(float f) {
    _Float16 h = (_Float16)f;   // RNE
    return *reinterpret_cast<unsigned short*>(&h);
}
__device__ __forceinline__ float h2f(unsigned short u) {
    _Float16 h = *reinterpret_cast<_Float16*>(&u);
    return (float)h;
}

__device__ __forceinline__ f32x4 mfma16h(half8 a, half8 b, f32x4 c) {
    return __builtin_amdgcn_mfma_f32_16x16x32_f16(a, b, c, 0, 0, 0);
}

// async global->LDS, 16B per lane; dest = lds base (wave-uniform) + lane*16
__device__ __forceinline__ void gload16(const unsigned short* g, unsigned short* l) {
    __builtin_amdgcn_global_load_lds(
        (const __attribute__((address_space(1))) unsigned int*)g,
        (__attribute__((address_space(3))) unsigned int*)l, 16, 0, 0);
}

// elementwise convert fp32 -> fp16 (RNE)
__global__ __launch_bounds__(256) void cvt_f16(
    const float* __restrict__ in, unsigned short* __restrict__ out, int n4)
{
    int i = blockIdx.x * 256 + threadIdx.x;
    if (i >= n4) return;
    float4 v = ((const float4*)in)[i];
    ushort4 o;
    o.x = f2h_bits(v.x); o.y = f2h_bits(v.y);
    o.z = f2h_bits(v.z); o.w = f2h_bits(v.w);
    ((ushort4*)out)[i] = o;
}

// pack conv weights f32 [c][tap] -> fp16 [tap][c]
__global__ __launch_bounds__(256) void pack_w16(
    const float* __restrict__ cw, unsigned short* __restrict__ wt)
{
    int c = blockIdx.x * 256 + threadIdx.x;
    if (c >= CDIM) return;
#pragma unroll
    for (int tap = 0; tap < 9; ++tap)
        wt[tap * CDIM + c] = f2h_bits(cw[c * 9 + tap]);
}

// C[m,n] = sum_k A[m,k]*B[n,k], fp16 operands, fp32 acc; OUT16 selects fp16/fp32 store.
// m97 structure + T1 XCD-chunked bijective block swizzle (total blocks % 8 == 0).
// Round-20 direct-store epilogue (LDS-epilogue variant regressed: 8-way bank conflicts).
template<int MT, int OUT16>
__global__ __launch_bounds__(256) void gemm_h(
    const unsigned short* __restrict__ Ah, int lda,
    const unsigned short* __restrict__ Bh, int ldb,
    void* __restrict__ Cp, int ldc, int N, int K)
{
    constexpr int BM = MT * 32;
    __shared__ __align__(16) unsigned short Ahs[BM * 64];
    __shared__ __align__(16) unsigned short Bhs[128 * 64];
    const int t = threadIdx.x;
    const int lane = t & 63;
    const int w = t >> 6;

    // XCD-chunked bijective swizzle: same-XCD-consecutive blocks share bm (A-panel L2 reuse)
    const int nbx = gridDim.x;
    const int total = nbx * gridDim.y;
    const int lin = blockIdx.y * nbx + blockIdx.x;
    const int chunk = total >> 3;
    const int newlin = (lin & 7) * chunk + (lin >> 3);
    const int bn = (newlin % nbx) * 128;
    const int bm = (newlin / nbx) * BM;

    const int wr = (w >> 1) * (MT * 16);
    const int wc = (w & 1) * 64;
    const int l15 = lane & 15;
    const int g   = lane >> 4;
    const int srow = lane >> 3;
    const int slot = lane & 7;

    f32x4 acc[MT][4];
#pragma unroll
    for (int m = 0; m < MT; ++m)
#pragma unroll
        for (int n = 0; n < 4; ++n) acc[m][n] = (f32x4){0.f, 0.f, 0.f, 0.f};

    for (int k0 = 0; k0 < K; k0 += 64) {
#pragma unroll
        for (int it = 0; it < MT; ++it) {            // A: BM rows
            int rowblk = w * (8 * MT) + it * 8;
            int row = rowblk + srow;
            int sl = (slot ^ (row & 7)) * 8;
            size_t goff = (size_t)(bm + row) * lda + k0 + sl;
            gload16(Ah + goff, Ahs + rowblk * 64);
        }
#pragma unroll
        for (int it = 0; it < 4; ++it) {             // B: 128 rows
            int rowblk = w * 32 + it * 8;
            int row = rowblk + srow;
            int n = bn + row; if (n > N - 1) n = N - 1;
            int sl = (slot ^ (row & 7)) * 8;
            size_t goff = (size_t)n * ldb + k0 + sl;
            gload16(Bh + goff, Bhs + rowblk * 64);
        }
        __syncthreads();

#pragma unroll
        for (int ks = 0; ks < 2; ++ks) {
            half8 av[MT], bv[4];
#pragma unroll
            for (int m = 0; m < MT; ++m) {
                int arow = wr + m * 16 + l15;
                int off = arow * 64 + (((ks * 4 + g) ^ (arow & 7)) << 3);
                av[m] = *(const half8*)&Ahs[off];
            }
#pragma unroll
            for (int n = 0; n < 4; ++n) {
                int brow = wc + n * 16 + l15;
                int off = brow * 64 + (((ks * 4 + g) ^ (brow & 7)) << 3);
                bv[n] = *(const half8*)&Bhs[off];
            }
#pragma unroll
            for (int m = 0; m < MT; ++m)
#pragma unroll
                for (int n = 0; n < 4; ++n)
                    acc[m][n] = mfma16h(av[m], bv[n], acc[m][n]);
        }
        __syncthreads();
    }

    const int col0 = bn + wc + l15;
    const int row0 = bm + wr + (g << 2);
#pragma unroll
    for (int n = 0; n < 4; ++n) {
        int col = col0 + n * 16;
        if (col < N) {
#pragma unroll
            for (int m = 0; m < MT; ++m)
#pragma unroll
                for (int ri = 0; ri < 4; ++ri) {
                    if (OUT16) {
                        ((unsigned short*)Cp)[(size_t)(row0 + m * 16 + ri) * ldc + col] =
                            f2h_bits(acc[m][n][ri]);
                    } else {
                        ((float*)Cp)[(size_t)(row0 + m * 16 + ri) * ldc + col] = acc[m][n][ri];
                    }
                }
        }
    }
}

// depthwise 3x3 conv (pad 1) + bias + SiLU. 8 channels x 4 w-positions per thread.
// T1 XCD-chunked swizzle: XCD k sweeps batch-image k in l-order -> halo rows stay in its L2.
__global__ __launch_bounds__(128) void conv_silu(
    const unsigned short* __restrict__ P, const unsigned short* __restrict__ wt,
    const float* __restrict__ cb, unsigned short* __restrict__ XC)
{
    const int t = threadIdx.x;
    if (t >= 112) return;
    const int c8 = t * 8;

    // bijective XCD-chunked remap of (bl, l-block)
    const int nbx = gridDim.x;                 // 784
    const int total = nbx * gridDim.y;         // %8==0
    const int lin = blockIdx.y * nbx + blockIdx.x;
    const int chunk = total >> 3;
    const int newlin = (lin & 7) * chunk + (lin >> 3);
    const int bl = newlin / nbx;
    const int l0 = (newlin % nbx) * 4;         // 4 outputs in one spatial row (56 % 4 == 0)

    const int h = l0 / WWD, w0 = l0 % WWD;

    float acc[4][8];
    float4 b0 = *(const float4*)&cb[c8];
    float4 b1 = *(const float4*)&cb[c8 + 4];
#pragma unroll
    for (int o = 0; o < 4; ++o) {
        acc[o][0] = b0.x; acc[o][1] = b0.y; acc[o][2] = b0.z; acc[o][3] = b0.w;
        acc[o][4] = b1.x; acc[o][5] = b1.y; acc[o][6] = b1.z; acc[o][7] = b1.w;
    }

    const unsigned short* pb = P + (size_t)bl * LL * PSTRIDE + DINNER + c8;

#pragma unroll
    for (int kh = 0; kh < 3; ++kh) {
        int h2 = h + kh - 1;
        bool hok = (unsigned)h2 < HH;
        float xf[6][8];
#pragma unroll
        for (int j = 0; j < 6; ++j) {
            int wj = w0 - 1 + j;
            if (hok && (unsigned)wj < WWD) {
                half8 v = *(const half8*)&pb[(size_t)(h2 * WWD + wj) * PSTRIDE];
#pragma unroll
                for (int q = 0; q < 8; ++q) xf[j][q] = (float)v[q];
            } else {
#pragma unroll
                for (int q = 0; q < 8; ++q) xf[j][q] = 0.f;
            }
        }
#pragma unroll
        for (int kw = 0; kw < 3; ++kw) {
            half8 wv = *(const half8*)&wt[(kh * 3 + kw) * CDIM + c8];
            float wf[8];
#pragma unroll
            for (int q = 0; q < 8; ++q) wf[q] = (float)wv[q];
#pragma unroll
            for (int o = 0; o < 4; ++o)
#pragma unroll
                for (int q = 0; q < 8; ++q)
                    acc[o][q] += wf[q] * xf[o + kw][q];
        }
    }

#pragma unroll
    for (int o = 0; o < 4; ++o) {
        half8 ov;
#pragma unroll
        for (int q = 0; q < 8; ++q) {
            float a = acc[o][q];
            ov[q] = (_Float16)(a / (1.f + __expf(-a)));
        }
        *(half8*)&XC[((size_t)bl * LL + l0 + o) * CDIM + c8] = ov;
    }
}

// KV partial via MFMA: KVpart[chunk][bl,h][p][s] = sum_{l in chunk} Bcf[l,s]*x[l,h*64+p].
// Transposed fp16 LDS staging (BshT[64s][TLD], XshT[64p][TLD]); cf folded into B at staging.
// Group size is runtime: gridDim.y.
__global__ __launch_bounds__(256) void kv_kernel(
    const unsigned short* __restrict__ XC, const unsigned short* __restrict__ P,
    const float* __restrict__ dt_bias, const float* __restrict__ A_log,
    float* __restrict__ KVpart)
{
    int h  = blockIdx.x;
    int bl = blockIdx.y;
    int lbase = blockIdx.z * 224;
    __shared__ __align__(16) unsigned short BshT[64 * TLD];
    __shared__ __align__(16) unsigned short XshT[64 * TLD];
    const int t = threadIdx.x;
    const int lane = t & 63;
    const int w = t >> 6;
    const int l15 = lane & 15;
    const int kg = lane >> 4;       // k-group 0..3
    const int pw = w * 16;          // wave's p-slab
    const int sl = t & 31;          // staging l row 0..31
    const int c8 = (t >> 5) * 8;    // staging channel group 0..56

    f32x4 acc[4];
#pragma unroll
    for (int sf = 0; sf < 4; ++sf) acc[sf] = (f32x4){0.f, 0.f, 0.f, 0.f};

    const unsigned short* xbase = XC + (size_t)bl * LL * CDIM;
    const unsigned short* pdt = P + (size_t)bl * LL * PSTRIDE + DINNER + CDIM + h;
    const float nA = -__expf(A_log[h]);
    const float db = dt_bias[h];

    // prefetch subtile 0
    ushort4 Bv[2], Xv[2];
    float dtv;
    {
        const unsigned short* r = xbase + (size_t)(lbase + sl) * CDIM;
        Bv[0] = *(const ushort4*)&r[DINNER + c8];
        Bv[1] = *(const ushort4*)&r[DINNER + c8 + 4];
        Xv[0] = *(const ushort4*)&r[h * HD + c8];
        Xv[1] = *(const ushort4*)&r[h * HD + c8 + 4];
        dtv = h2f(pdt[(size_t)(lbase + sl) * PSTRIDE]);
    }

    for (int c = 0; c < 7; ++c) {
        __syncthreads();   // previous compute done; LDS free
        {
            float x = dtv + db;
            float sp = (x > 20.f) ? x : log1pf(__expf(x));
            float cfr = nA * sp;
#pragma unroll
            for (int i = 0; i < 4; ++i) {
                BshT[(c8 + i) * TLD + sl]     = f2h_bits(h2f(((const unsigned short*)&Bv[0])[i]) * cfr);
                BshT[(c8 + 4 + i) * TLD + sl] = f2h_bits(h2f(((const unsigned short*)&Bv[1])[i]) * cfr);
                XshT[(c8 + i) * TLD + sl]     = ((const unsigned short*)&Xv[0])[i];
                XshT[(c8 + 4 + i) * TLD + sl] = ((const unsigned short*)&Xv[1])[i];
            }
        }
        __syncthreads();   // tile ready

        if (c < 6) {       // issue next subtile's loads; land during MFMA
            int lrow = lbase + (c + 1) * 32 + sl;
            const unsigned short* r = xbase + (size_t)lrow * CDIM;
            Bv[0] = *(const ushort4*)&r[DINNER + c8];
            Bv[1] = *(const ushort4*)&r[DINNER + c8 + 4];
            Xv[0] = *(const ushort4*)&r[h * HD + c8];
            Xv[1] = *(const ushort4*)&r[h * HD + c8 + 4];
            dtv = h2f(pdt[(size_t)lrow * PSTRIDE]);
        }

        // MFMA: A = X^T rows (p), B = Bcf^T rows (s), k = 32 l of this subtile
        half8 av = *(const half8*)&XshT[(pw + l15) * TLD + kg * 8];
#pragma unroll
        for (int sf = 0; sf < 4; ++sf) {
            half8 bv = *(const half8*)&BshT[(sf * 16 + l15) * TLD + kg * 8];
            acc[sf] = mfma16h(av, bv, acc[sf]);
        }
    }

    // C/D layout: col(s) = l15, row(p) = kg*4 + ri (within wave's p-slab)
    float* outp = KVpart +
        ((size_t)blockIdx.z * gridDim.y * NH + (size_t)bl * NH + h) * (HD * DSTATE);
#pragma unroll
    for (int sf = 0; sf < 4; ++sf)
#pragma unroll
        for (int ri = 0; ri < 4; ++ri)
            outp[(size_t)(pw + kg * 4 + ri) * DSTATE + sf * 16 + l15] = acc[sf][ri];
}

// sum NCHUNK partials (fp32, fixed order) -> fp16 KV16
__global__ __launch_bounds__(256) void kv_reduce(
    const float* __restrict__ KVpart, unsigned short* __restrict__ KV16, int n4)
{
    int i = blockIdx.x * 256 + threadIdx.x;
    if (i >= n4) return;
    float4 s = ((const float4*)KVpart)[i];
#pragma unroll
    for (int c = 1; c < NCHUNK; ++c) {
        float4 v = ((const float4*)KVpart)[(size_t)c * n4 + i];
        s.x += v.x; s.y += v.y; s.z += v.z; s.w += v.w;
    }
    ushort4 o;
    o.x = f2h_bits(s.x); o.y = f2h_bits(s.y);
    o.z = f2h_bits(s.z); o.w = f2h_bits(s.w);
    ((ushort4*)KV16)[i] = o;
}

// Fused: yg = (Cmat @ KVcat + x*D) * silu(z); LayerNorm(768); y fp16 -> P z cols.
// LDS-staged: z/x/C tiles coalesced into LDS; gating/LN from LDS; bulk write-back.
__global__ __launch_bounds__(256) void ckv_ln(
    unsigned short* __restrict__ P, const unsigned short* __restrict__ XC,
    const unsigned short* __restrict__ KV16, const float* __restrict__ Dp,
    const float* __restrict__ ln_g, const float* __restrict__ ln_b)
{
    const int t = threadIdx.x;
    const int lane = t & 63;
    const int w = t >> 6;
    const int r0 = blockIdx.x * 16;
    const int bl = blockIdx.y;
    const int l15 = lane & 15;
    const int q4 = lane >> 4;          // row-quarter
    const int dw = w * 192;

    __shared__ float ps1[4][16], ps2[4][16];
    __shared__ __align__(16) unsigned short zs[16][YLD];
    __shared__ __align__(16) unsigned short xs[16][YLD];
    __shared__ __align__(16) unsigned short Cs[16][72];

    const size_t gbase = (size_t)bl * LL + r0;

    // stage z (P cols 0..767), x (XC cols 0..767) coalesced; C tile (cols 832..895)
#pragma unroll
    for (int pass = 0; pass < 6; ++pass) {
        int idx = pass * 256 + t;
        int row = idx / 96, slot = idx % 96;
        *(half8*)&zs[row][slot * 8] = *(const half8*)&P[(gbase + row) * PSTRIDE + slot * 8];
        *(half8*)&xs[row][slot * 8] = *(const half8*)&XC[(gbase + row) * CDIM + slot * 8];
    }
    if (t < 128) {
        int row = t >> 3, slot = t & 7;
        *(half8*)&Cs[row][slot * 8] =
            *(const half8*)&XC[(gbase + row) * CDIM + DINNER + DSTATE + slot * 8];
    }
    __syncthreads();

    f32x4 acc[12];
#pragma unroll
    for (int n = 0; n < 12; ++n) acc[n] = (f32x4){0.f, 0.f, 0.f, 0.f};

    const unsigned short* kvb = KV16 + (size_t)bl * NH * HD * DSTATE;

    float dch[12];
#pragma unroll
    for (int n = 0; n < 12; ++n) dch[n] = Dp[(dw + n * 16) >> 6];

#pragma unroll
    for (int ks = 0; ks < 2; ++ks) {
        int koff = ks * 32 + q4 * 8;
        half8 av = *(const half8*)&Cs[l15][koff];
#pragma unroll
        for (int n = 0; n < 12; ++n) {
            int d = dw + n * 16 + l15;
            int hh = d >> 6, p = d & 63;
            half8 bv = *(const half8*)&kvb[((size_t)hh * HD + p) * DSTATE + koff];
            acc[n] = mfma16h(av, bv, acc[n]);
        }
    }

    // gate from LDS + per-row partial sums
    float s1[4], s2[4];
#pragma unroll
    for (int ri = 0; ri < 4; ++ri) {
        int rloc = q4 * 4 + ri;
        float a1 = 0.f, a2 = 0.f;
#pragma unroll
        for (int n = 0; n < 12; ++n) {
            int d = dw + n * 16 + l15;
            float x = h2f(xs[rloc][d]);
            float z = h2f(zs[rloc][d]);
            float sz = z / (1.f + __expf(-z));
            float yg = (acc[n][ri] + x * dch[n]) * sz;
            acc[n][ri] = yg;
            a1 += yg; a2 += yg * yg;
        }
#pragma unroll
        for (int off = 1; off < 16; off <<= 1) {
            a1 += __shfl_xor(a1, off);
            a2 += __shfl_xor(a2, off);
        }
        s1[ri] = a1; s2[ri] = a2;
    }
    if (l15 == 0) {
#pragma unroll
        for (int ri = 0; ri < 4; ++ri) {
            ps1[w][q4 * 4 + ri] = s1[ri];
            ps2[w][q4 * 4 + ri] = s2[ri];
        }
    }
    __syncthreads();

    // per-lane gamma/beta for its 12 columns
    float gg[12], bb2[12];
#pragma unroll
    for (int n = 0; n < 12; ++n) {
        int d = dw + n * 16 + l15;
        gg[n] = ln_g[d];
        bb2[n] = ln_b[d];
    }

#pragma unroll
    for (int ri = 0; ri < 4; ++ri) {
        int rloc = q4 * 4 + ri;
        float S1 = ps1[0][rloc] + ps1[1][rloc] + ps1[2][rloc] + ps1[3][rloc];
        float S2 = ps2[0][rloc] + ps2[1][rloc] + ps2[2][rloc] + ps2[3][rloc];
        float mu = S1 * (1.f / 768.f);
        float var = S2 * (1.f / 768.f) - mu * mu;
        float rstd = rsqrtf(var + LNEPS);
#pragma unroll
        for (int n = 0; n < 12; ++n) {
            int d = dw + n * 16 + l15;
            zs[rloc][d] = f2h_bits((acc[n][ri] - mu) * rstd * gg[n] + bb2[n]);
        }
    }
    __syncthreads();

    // bulk coalesced write-back of y into P z cols
#pragma unroll
    for (int pass = 0; pass < 6; ++pass) {
        int idx = pass * 256 + t;
        int row = idx / 96, slot = idx % 96;
        *(half8*)&P[(gbase + row) * PSTRIDE + slot * 8] = *(const half8*)&zs[row][slot * 8];
    }
}

extern "C" void kernel_launch(void* const* d_in, const int* in_sizes, int n_in,
                              void* d_out, int out_size, void* d_ws, size_t ws_size,
                              hipStream_t stream)
{
    const float* u       = (const float*)d_in[0];
    const float* W_in    = (const float*)d_in[1];
    const float* conv_w  = (const float*)d_in[2];
    const float* conv_b  = (const float*)d_in[3];
    const float* dt_bias = (const float*)d_in[4];
    const float* A_log   = (const float*)d_in[5];
    const float* Dp      = (const float*)d_in[6];
    const float* ln_g    = (const float*)d_in[7];
    const float* ln_b    = (const float*)d_in[8];
    const float* W_out   = (const float*)d_in[9];
    float* out = (float*)d_out;

    const int B = in_sizes[0] / (LL * DMODEL);   // 16
    const int M = B * LL;                        // 50176

    // runtime group size: single pass if workspace allows (deterministic in ws_size)
    auto footprint = [&](int grp) -> size_t {
        size_t gm = (size_t)grp * LL;
        size_t kvsz = (size_t)grp * NH * HD * DSTATE;
        size_t n = gm * PSTRIDE * 2            // P
                 + gm * CDIM * 2               // XC
                 + (size_t)NCHUNK * kvsz * 4   // KVpart
                 + kvsz * 2                    // KV16
                 + (size_t)M * DMODEL * 2      // u16
                 + (size_t)DPROJ * DMODEL * 2  // Wi16
                 + (size_t)DMODEL * DINNER * 2 // Wo16
                 + 9 * CDIM * 2;               // wt16
        return n + 4096;
    };
    const int grp = (B % 16 == 0 && ws_size >= footprint(16)) ? 16 : 8;
    const size_t gm = (size_t)grp * LL;
    const size_t kvsz = (size_t)grp * NH * HD * DSTATE;

    unsigned short* P  = (unsigned short*)d_ws;             // gm*PSTRIDE fp16
    unsigned short* XC = P + gm * PSTRIDE;                  // gm*896 fp16
    float* KVpart = (float*)(XC + gm * CDIM);               // NCHUNK*kvsz f32
    unsigned short* KV16 = (unsigned short*)(KVpart + (size_t)NCHUNK * kvsz);
    unsigned short* u16  = KV16 + kvsz;                     // M*384
    unsigned short* Wi16 = u16 + (size_t)M * DMODEL;        // 1676*384
    unsigned short* Wo16 = Wi16 + (size_t)DPROJ * DMODEL;   // 384*768
    unsigned short* wt16 = Wo16 + (size_t)DMODEL * DINNER;  // 9*896

    // one-time fp16 converts / packs
    cvt_f16<<<((size_t)M * DMODEL / 4 + 255) / 256, 256, 0, stream>>>(u, u16, M * DMODEL / 4);
    cvt_f16<<<(DPROJ * DMODEL / 4 + 255) / 256, 256, 0, stream>>>(W_in, Wi16, DPROJ * DMODEL / 4);
    cvt_f16<<<(DMODEL * DINNER / 4 + 255) / 256, 256, 0, stream>>>(W_out, Wo16, DMODEL * DINNER / 4);
    pack_w16<<<(CDIM + 255) / 256, 256, 0, stream>>>(conv_w, wt16);

    const int nkv4 = (int)(kvsz / 4);

    for (int b0 = 0; b0 < B; b0 += grp) {
        // 1) P = u_grp @ W_in^T  (fp16 MFMA, fp16 store; grid %8==0, XCD-swizzled)
        gemm_h<4, 1><<<dim3(14, gm / 128), 256, 0, stream>>>(
            u16 + (size_t)b0 * LL * DMODEL, DMODEL, Wi16, DMODEL, P, PSTRIDE, DPROJ, DMODEL);

        // 2) depthwise conv + SiLU (8ch x 4w per thread; grid %8==0, XCD-swizzled)
        conv_silu<<<dim3(LL / 4, grp), 128, 0, stream>>>(P, wt16, conv_b, XC);

        // 3) KV partials via MFMA (transposed fp16 staging, cf folded into B)
        kv_kernel<<<dim3(NH, grp, NCHUNK), 256, 0, stream>>>(XC, P, dt_bias, A_log, KVpart);

        // 4) reduce partials -> fp16 KV16
        kv_reduce<<<(nkv4 + 255) / 256, 256, 0, stream>>>(KVpart, KV16, nkv4);

        // 5) fused yg = (C@KV + x*D)*silu(z) + LayerNorm -> y fp16 into P z cols (LDS-staged)
        ckv_ln<<<dim3(LL / 16, grp), 256, 0, stream>>>(P, XC, KV16, Dp, ln_g, ln_b);

        // 6) out_grp = y @ W_out^T  (fp16 A in P, fp32 out; grid %8==0, swizzled)
        gemm_h<2, 0><<<dim3(3, gm / 64), 256, 0, stream>>>(
            P, PSTRIDE, Wo16, DINNER,
            out + (size_t)b0 * LL * DMODEL, DMODEL, DMODEL, DINNER);
    }
}

// Round 23
// 375.031 us; speedup vs baseline: 1.1345x; 1.1166x over previous
//
#include <hip/hip_runtime.h>
#include <hip/hip_bf16.h>

#define LL 3136
#define HH 56
#define WWD 56
#define DMODEL 384
#define DINNER 768
#define NH 12
#define HD 64
#define DSTATE 64
#define CDIM 896
#define DPROJ 1676
#define PSTRIDE 1680           // padded P row stride in ushorts (3360 B, 16B-aligned rows)
#define LNEPS 1e-5f
#define NCHUNK 14              // KV L-chunks per (bl,h)
#define TLD 40                 // transposed-LDS row stride (ushorts)
#define YLD 776                // z/x LDS row stride (ushorts)

typedef __attribute__((ext_vector_type(8))) _Float16 half8;
typedef __attribute__((ext_vector_type(2))) _Float16 half2v;
typedef __attribute__((ext_vector_type(4))) float f32x4;

__device__ __forceinline__ unsigned short f2h_bits(float f) {
    _Float16 h = (_Float16)f;   // RNE
    return *reinterpret_cast<unsigned short*>(&h);
}
__device__ __forceinline__ float h2f(unsigned short u) {
    _Float16 h = *reinterpret_cast<_Float16*>(&u);
    return (float)h;
}

__device__ __forceinline__ f32x4 mfma16h(half8 a, half8 b, f32x4 c) {
    return __builtin_amdgcn_mfma_f32_16x16x32_f16(a, b, c, 0, 0, 0);
}

// async global->LDS, 16B per lane; dest = lds base (wave-uniform) + lane*16
__device__ __forceinline__ void gload16(const unsigned short* g, unsigned short* l) {
    __builtin_amdgcn_global_load_lds(
        (const __attribute__((address_space(1))) unsigned int*)g,
        (__attribute__((address_space(3))) unsigned int*)l, 16, 0, 0);
}

// elementwise convert fp32 -> fp16 (RNE)
__global__ __launch_bounds__(256) void cvt_f16(
    const float* __restrict__ in, unsigned short* __restrict__ out, int n4)
{
    int i = blockIdx.x * 256 + threadIdx.x;
    if (i >= n4) return;
    float4 v = ((const float4*)in)[i];
    ushort4 o;
    o.x = f2h_bits(v.x); o.y = f2h_bits(v.y);
    o.z = f2h_bits(v.z); o.w = f2h_bits(v.w);
    ((ushort4*)out)[i] = o;
}

// pack conv weights f32 [c][tap] -> fp16 [tap][c]
__global__ __launch_bounds__(256) void pack_w16(
    const float* __restrict__ cw, unsigned short* __restrict__ wt)
{
    int c = blockIdx.x * 256 + threadIdx.x;
    if (c >= CDIM) return;
#pragma unroll
    for (int tap = 0; tap < 9; ++tap)
        wt[tap * CDIM + c] = f2h_bits(cw[c * 9 + tap]);
}

// C[m,n] = sum_k A[m,k]*B[n,k], fp16 operands, fp32 acc; OUT16 selects fp16/fp32 store.
// m97 structure + T1 XCD-chunked bijective block swizzle (total blocks % 8 == 0).
template<int MT, int OUT16>
__global__ __launch_bounds__(256) void gemm_h(
    const unsigned short* __restrict__ Ah, int lda,
    const unsigned short* __restrict__ Bh, int ldb,
    void* __restrict__ Cp, int ldc, int N, int K)
{
    constexpr int BM = MT * 32;
    __shared__ __align__(16) unsigned short Ahs[BM * 64];
    __shared__ __align__(16) unsigned short Bhs[128 * 64];
    const int t = threadIdx.x;
    const int lane = t & 63;
    const int w = t >> 6;

    // XCD-chunked bijective swizzle: same-XCD-consecutive blocks share bm (A-panel L2 reuse)
    const int nbx = gridDim.x;
    const int total = nbx * gridDim.y;
    const int lin = blockIdx.y * nbx + blockIdx.x;
    const int chunk = total >> 3;
    const int newlin = (lin & 7) * chunk + (lin >> 3);
    const int bn = (newlin % nbx) * 128;
    const int bm = (newlin / nbx) * BM;

    const int wr = (w >> 1) * (MT * 16);
    const int wc = (w & 1) * 64;
    const int l15 = lane & 15;
    const int g   = lane >> 4;
    const int srow = lane >> 3;
    const int slot = lane & 7;

    f32x4 acc[MT][4];
#pragma unroll
    for (int m = 0; m < MT; ++m)
#pragma unroll
        for (int n = 0; n < 4; ++n) acc[m][n] = (f32x4){0.f, 0.f, 0.f, 0.f};

    for (int k0 = 0; k0 < K; k0 += 64) {
#pragma unroll
        for (int it = 0; it < MT; ++it) {            // A: BM rows
            int rowblk = w * (8 * MT) + it * 8;
            int row = rowblk + srow;
            int sl = (slot ^ (row & 7)) * 8;
            size_t goff = (size_t)(bm + row) * lda + k0 + sl;
            gload16(Ah + goff, Ahs + rowblk * 64);
        }
#pragma unroll
        for (int it = 0; it < 4; ++it) {             // B: 128 rows
            int rowblk = w * 32 + it * 8;
            int row = rowblk + srow;
            int n = bn + row; if (n > N - 1) n = N - 1;
            int sl = (slot ^ (row & 7)) * 8;
            size_t goff = (size_t)n * ldb + k0 + sl;
            gload16(Bh + goff, Bhs + rowblk * 64);
        }
        __syncthreads();

#pragma unroll
        for (int ks = 0; ks < 2; ++ks) {
            half8 av[MT], bv[4];
#pragma unroll
            for (int m = 0; m < MT; ++m) {
                int arow = wr + m * 16 + l15;
                int off = arow * 64 + (((ks * 4 + g) ^ (arow & 7)) << 3);
                av[m] = *(const half8*)&Ahs[off];
            }
#pragma unroll
            for (int n = 0; n < 4; ++n) {
                int brow = wc + n * 16 + l15;
                int off = brow * 64 + (((ks * 4 + g) ^ (brow & 7)) << 3);
                bv[n] = *(const half8*)&Bhs[off];
            }
#pragma unroll
            for (int m = 0; m < MT; ++m)
#pragma unroll
                for (int n = 0; n < 4; ++n)
                    acc[m][n] = mfma16h(av[m], bv[n], acc[m][n]);
        }
        __syncthreads();
    }

    const int col0 = bn + wc + l15;
    const int row0 = bm + wr + (g << 2);
#pragma unroll
    for (int n = 0; n < 4; ++n) {
        int col = col0 + n * 16;
        if (col < N) {
#pragma unroll
            for (int m = 0; m < MT; ++m)
#pragma unroll
                for (int ri = 0; ri < 4; ++ri) {
                    if (OUT16) {
                        ((unsigned short*)Cp)[(size_t)(row0 + m * 16 + ri) * ldc + col] =
                            f2h_bits(acc[m][n][ri]);
                    } else {
                        ((float*)Cp)[(size_t)(row0 + m * 16 + ri) * ldc + col] = acc[m][n][ri];
                    }
                }
        }
    }
}

// depthwise 3x3 conv (pad 1) + bias + SiLU. 8 channels x 4 w-positions per thread.
// Packed fp16 math (v_pk_fma_f16): no per-tap converts; fp32 only for final SiLU.
// T1 XCD-chunked swizzle: XCD k sweeps batch-image k in l-order.
__global__ __launch_bounds__(128) void conv_silu(
    const unsigned short* __restrict__ P, const unsigned short* __restrict__ wt,
    const float* __restrict__ cb, unsigned short* __restrict__ XC)
{
    const int t = threadIdx.x;
    if (t >= 112) return;
    const int c8 = t * 8;

    // bijective XCD-chunked remap of (bl, l-block)
    const int nbx = gridDim.x;                 // 784
    const int total = nbx * gridDim.y;         // %8==0
    const int lin = blockIdx.y * nbx + blockIdx.x;
    const int chunk = total >> 3;
    const int newlin = (lin & 7) * chunk + (lin >> 3);
    const int bl = newlin / nbx;
    const int l0 = (newlin % nbx) * 4;         // 4 outputs in one spatial row (56 % 4 == 0)

    const int h = l0 / WWD, w0 = l0 % WWD;

    half2v acc2[4][4];
    {
        float4 b0 = *(const float4*)&cb[c8];
        float4 b1 = *(const float4*)&cb[c8 + 4];
        half2v bias[4];
        bias[0] = (half2v){(_Float16)b0.x, (_Float16)b0.y};
        bias[1] = (half2v){(_Float16)b0.z, (_Float16)b0.w};
        bias[2] = (half2v){(_Float16)b1.x, (_Float16)b1.y};
        bias[3] = (half2v){(_Float16)b1.z, (_Float16)b1.w};
#pragma unroll
        for (int o = 0; o < 4; ++o)
#pragma unroll
            for (int q = 0; q < 4; ++q) acc2[o][q] = bias[q];
    }

    const unsigned short* pb = P + (size_t)bl * LL * PSTRIDE + DINNER + c8;

#pragma unroll
    for (int kh = 0; kh < 3; ++kh) {
        int h2 = h + kh - 1;
        bool hok = (unsigned)h2 < HH;
        half2v xf2[6][4];
#pragma unroll
        for (int j = 0; j < 6; ++j) {
            int wj = w0 - 1 + j;
            if (hok && (unsigned)wj < WWD) {
                half8 v = *(const half8*)&pb[(size_t)(h2 * WWD + wj) * PSTRIDE];
                *(half8*)&xf2[j][0] = v;
            } else {
                half2v z = (half2v){(_Float16)0.f, (_Float16)0.f};
#pragma unroll
                for (int q = 0; q < 4; ++q) xf2[j][q] = z;
            }
        }
#pragma unroll
        for (int kw = 0; kw < 3; ++kw) {
            half2v wv2[4];
            *(half8*)&wv2[0] = *(const half8*)&wt[(kh * 3 + kw) * CDIM + c8];
#pragma unroll
            for (int o = 0; o < 4; ++o)
#pragma unroll
                for (int q = 0; q < 4; ++q)
                    acc2[o][q] = wv2[q] * xf2[o + kw][q] + acc2[o][q];   // v_pk_fma_f16
        }
    }

#pragma unroll
    for (int o = 0; o < 4; ++o) {
        half8 ov;
#pragma unroll
        for (int q = 0; q < 4; ++q) {
#pragma unroll
            for (int e = 0; e < 2; ++e) {
                float a = (float)acc2[o][q][e];
                ov[q * 2 + e] = (_Float16)(a / (1.f + __expf(-a)));
            }
        }
        *(half8*)&XC[((size_t)bl * LL + l0 + o) * CDIM + c8] = ov;
    }
}

// KV partial via MFMA: KVpart[chunk][bl,h][p][s] = sum_{l in chunk} Bcf[l,s]*x[l,h*64+p].
// Transposed fp16 LDS staging (BshT[64s][TLD], XshT[64p][TLD]); cf folded into B at staging.
// Group size is runtime: gridDim.y.
__global__ __launch_bounds__(256) void kv_kernel(
    const unsigned short* __restrict__ XC, const unsigned short* __restrict__ P,
    const float* __restrict__ dt_bias, const float* __restrict__ A_log,
    float* __restrict__ KVpart)
{
    int h  = blockIdx.x;
    int bl = blockIdx.y;
    int lbase = blockIdx.z * 224;
    __shared__ __align__(16) unsigned short BshT[64 * TLD];
    __shared__ __align__(16) unsigned short XshT[64 * TLD];
    const int t = threadIdx.x;
    const int lane = t & 63;
    const int w = t >> 6;
    const int l15 = lane & 15;
    const int kg = lane >> 4;       // k-group 0..3
    const int pw = w * 16;          // wave's p-slab
    const int sl = t & 31;          // staging l row 0..31
    const int c8 = (t >> 5) * 8;    // staging channel group 0..56

    f32x4 acc[4];
#pragma unroll
    for (int sf = 0; sf < 4; ++sf) acc[sf] = (f32x4){0.f, 0.f, 0.f, 0.f};

    const unsigned short* xbase = XC + (size_t)bl * LL * CDIM;
    const unsigned short* pdt = P + (size_t)bl * LL * PSTRIDE + DINNER + CDIM + h;
    const float nA = -__expf(A_log[h]);
    const float db = dt_bias[h];

    // prefetch subtile 0
    ushort4 Bv[2], Xv[2];
    float dtv;
    {
        const unsigned short* r = xbase + (size_t)(lbase + sl) * CDIM;
        Bv[0] = *(const ushort4*)&r[DINNER + c8];
        Bv[1] = *(const ushort4*)&r[DINNER + c8 + 4];
        Xv[0] = *(const ushort4*)&r[h * HD + c8];
        Xv[1] = *(const ushort4*)&r[h * HD + c8 + 4];
        dtv = h2f(pdt[(size_t)(lbase + sl) * PSTRIDE]);
    }

    for (int c = 0; c < 7; ++c) {
        __syncthreads();   // previous compute done; LDS free
        {
            float x = dtv + db;
            float sp = (x > 20.f) ? x : log1pf(__expf(x));
            float cfr = nA * sp;
#pragma unroll
            for (int i = 0; i < 4; ++i) {
                BshT[(c8 + i) * TLD + sl]     = f2h_bits(h2f(((const unsigned short*)&Bv[0])[i]) * cfr);
                BshT[(c8 + 4 + i) * TLD + sl] = f2h_bits(h2f(((const unsigned short*)&Bv[1])[i]) * cfr);
                XshT[(c8 + i) * TLD + sl]     = ((const unsigned short*)&Xv[0])[i];
                XshT[(c8 + 4 + i) * TLD + sl] = ((const unsigned short*)&Xv[1])[i];
            }
        }
        __syncthreads();   // tile ready

        if (c < 6) {       // issue next subtile's loads; land during MFMA
            int lrow = lbase + (c + 1) * 32 + sl;
            const unsigned short* r = xbase + (size_t)lrow * CDIM;
            Bv[0] = *(const ushort4*)&r[DINNER + c8];
            Bv[1] = *(const ushort4*)&r[DINNER + c8 + 4];
            Xv[0] = *(const ushort4*)&r[h * HD + c8];
            Xv[1] = *(const ushort4*)&r[h * HD + c8 + 4];
            dtv = h2f(pdt[(size_t)lrow * PSTRIDE]);
        }

        // MFMA: A = X^T rows (p), B = Bcf^T rows (s), k = 32 l of this subtile
        half8 av = *(const half8*)&XshT[(pw + l15) * TLD + kg * 8];
#pragma unroll
        for (int sf = 0; sf < 4; ++sf) {
            half8 bv = *(const half8*)&BshT[(sf * 16 + l15) * TLD + kg * 8];
            acc[sf] = mfma16h(av, bv, acc[sf]);
        }
    }

    // C/D layout: col(s) = l15, row(p) = kg*4 + ri (within wave's p-slab)
    float* outp = KVpart +
        ((size_t)blockIdx.z * gridDim.y * NH + (size_t)bl * NH + h) * (HD * DSTATE);
#pragma unroll
    for (int sf = 0; sf < 4; ++sf)
#pragma unroll
        for (int ri = 0; ri < 4; ++ri)
            outp[(size_t)(pw + kg * 4 + ri) * DSTATE + sf * 16 + l15] = acc[sf][ri];
}

// sum NCHUNK partials (fp32, fixed order) -> fp16 KV16
__global__ __launch_bounds__(256) void kv_reduce(
    const float* __restrict__ KVpart, unsigned short* __restrict__ KV16, int n4)
{
    int i = blockIdx.x * 256 + threadIdx.x;
    if (i >= n4) return;
    float4 s = ((const float4*)KVpart)[i];
#pragma unroll
    for (int c = 1; c < NCHUNK; ++c) {
        float4 v = ((const float4*)KVpart)[(size_t)c * n4 + i];
        s.x += v.x; s.y += v.y; s.z += v.z; s.w += v.w;
    }
    ushort4 o;
    o.x = f2h_bits(s.x); o.y = f2h_bits(s.y);
    o.z = f2h_bits(s.z); o.w = f2h_bits(s.w);
    ((ushort4*)KV16)[i] = o;
}

// Fused: yg = (Cmat @ KVcat + x*D) * silu(z); LayerNorm(768); y fp16 -> P z cols.
// LDS-staged: z/x/C tiles coalesced into LDS; gating/LN from LDS; bulk write-back.
__global__ __launch_bounds__(256) void ckv_ln(
    unsigned short* __restrict__ P, const unsigned short* __restrict__ XC,
    const unsigned short* __restrict__ KV16, const float* __restrict__ Dp,
    const float* __restrict__ ln_g, const float* __restrict__ ln_b)
{
    const int t = threadIdx.x;
    const int lane = t & 63;
    const int w = t >> 6;
    const int r0 = blockIdx.x * 16;
    const int bl = blockIdx.y;
    const int l15 = lane & 15;
    const int q4 = lane >> 4;          // row-quarter
    const int dw = w * 192;

    __shared__ float ps1[4][16], ps2[4][16];
    __shared__ __align__(16) unsigned short zs[16][YLD];
    __shared__ __align__(16) unsigned short xs[16][YLD];
    __shared__ __align__(16) unsigned short Cs[16][72];

    const size_t gbase = (size_t)bl * LL + r0;

    // stage z (P cols 0..767), x (XC cols 0..767) coalesced; C tile (cols 832..895)
#pragma unroll
    for (int pass = 0; pass < 6; ++pass) {
        int idx = pass * 256 + t;
        int row = idx / 96, slot = idx % 96;
        *(half8*)&zs[row][slot * 8] = *(const half8*)&P[(gbase + row) * PSTRIDE + slot * 8];
        *(half8*)&xs[row][slot * 8] = *(const half8*)&XC[(gbase + row) * CDIM + slot * 8];
    }
    if (t < 128) {
        int row = t >> 3, slot = t & 7;
        *(half8*)&Cs[row][slot * 8] =
            *(const half8*)&XC[(gbase + row) * CDIM + DINNER + DSTATE + slot * 8];
    }
    __syncthreads();

    f32x4 acc[12];
#pragma unroll
    for (int n = 0; n < 12; ++n) acc[n] = (f32x4){0.f, 0.f, 0.f, 0.f};

    const unsigned short* kvb = KV16 + (size_t)bl * NH * HD * DSTATE;

    float dch[12];
#pragma unroll
    for (int n = 0; n < 12; ++n) dch[n] = Dp[(dw + n * 16) >> 6];

#pragma unroll
    for (int ks = 0; ks < 2; ++ks) {
        int koff = ks * 32 + q4 * 8;
        half8 av = *(const half8*)&Cs[l15][koff];
#pragma unroll
        for (int n = 0; n < 12; ++n) {
            int d = dw + n * 16 + l15;
            int hh = d >> 6, p = d & 63;
            half8 bv = *(const half8*)&kvb[((size_t)hh * HD + p) * DSTATE + koff];
            acc[n] = mfma16h(av, bv, acc[n]);
        }
    }

    // gate from LDS + per-row partial sums
    float s1[4], s2[4];
#pragma unroll
    for (int ri = 0; ri < 4; ++ri) {
        int rloc = q4 * 4 + ri;
        float a1 = 0.f, a2 = 0.f;
#pragma unroll
        for (int n = 0; n < 12; ++n) {
            int d = dw + n * 16 + l15;
            float x = h2f(xs[rloc][d]);
            float z = h2f(zs[rloc][d]);
            float sz = z / (1.f + __expf(-z));
            float yg = (acc[n][ri] + x * dch[n]) * sz;
            acc[n][ri] = yg;
            a1 += yg; a2 += yg * yg;
        }
#pragma unroll
        for (int off = 1; off < 16; off <<= 1) {
            a1 += __shfl_xor(a1, off);
            a2 += __shfl_xor(a2, off);
        }
        s1[ri] = a1; s2[ri] = a2;
    }
    if (l15 == 0) {
#pragma unroll
        for (int ri = 0; ri < 4; ++ri) {
            ps1[w][q4 * 4 + ri] = s1[ri];
            ps2[w][q4 * 4 + ri] = s2[ri];
        }
    }
    __syncthreads();

    // per-lane gamma/beta for its 12 columns
    float gg[12], bb2[12];
#pragma unroll
    for (int n = 0; n < 12; ++n) {
        int d = dw + n * 16 + l15;
        gg[n] = ln_g[d];
        bb2[n] = ln_b[d];
    }

#pragma unroll
    for (int ri = 0; ri < 4; ++ri) {
        int rloc = q4 * 4 + ri;
        float S1 = ps1[0][rloc] + ps1[1][rloc] + ps1[2][rloc] + ps1[3][rloc];
        float S2 = ps2[0][rloc] + ps2[1][rloc] + ps2[2][rloc] + ps2[3][rloc];
        float mu = S1 * (1.f / 768.f);
        float var = S2 * (1.f / 768.f) - mu * mu;
        float rstd = rsqrtf(var + LNEPS);
#pragma unroll
        for (int n = 0; n < 12; ++n) {
            int d = dw + n * 16 + l15;
            zs[rloc][d] = f2h_bits((acc[n][ri] - mu) * rstd * gg[n] + bb2[n]);
        }
    }
    __syncthreads();

    // bulk coalesced write-back of y into P z cols
#pragma unroll
    for (int pass = 0; pass < 6; ++pass) {
        int idx = pass * 256 + t;
        int row = idx / 96, slot = idx % 96;
        *(half8*)&P[(gbase + row) * PSTRIDE + slot * 8] = *(const half8*)&zs[row][slot * 8];
    }
}

extern "C" void kernel_launch(void* const* d_in, const int* in_sizes, int n_in,
                              void* d_out, int out_size, void* d_ws, size_t ws_size,
                              hipStream_t stream)
{
    const float* u       = (const float*)d_in[0];
    const float* W_in    = (const float*)d_in[1];
    const float* conv_w  = (const float*)d_in[2];
    const float* conv_b  = (const float*)d_in[3];
    const float* dt_bias = (const float*)d_in[4];
    const float* A_log   = (const float*)d_in[5];
    const float* Dp      = (const float*)d_in[6];
    const float* ln_g    = (const float*)d_in[7];
    const float* ln_b    = (const float*)d_in[8];
    const float* W_out   = (const float*)d_in[9];
    float* out = (float*)d_out;

    const int B = in_sizes[0] / (LL * DMODEL);   // 16
    const int M = B * LL;                        // 50176

    // runtime group size: single pass if workspace allows (deterministic in ws_size)
    auto footprint = [&](int grp) -> size_t {
        size_t gm = (size_t)grp * LL;
        size_t kvsz = (size_t)grp * NH * HD * DSTATE;
        size_t n = gm * PSTRIDE * 2            // P
                 + gm * CDIM * 2               // XC
                 + (size_t)NCHUNK * kvsz * 4   // KVpart
                 + kvsz * 2                    // KV16
                 + (size_t)M * DMODEL * 2      // u16
                 + (size_t)DPROJ * DMODEL * 2  // Wi16
                 + (size_t)DMODEL * DINNER * 2 // Wo16
                 + 9 * CDIM * 2;               // wt16
        return n + 4096;
    };
    const int grp = (B % 16 == 0 && ws_size >= footprint(16)) ? 16 : 8;
    const size_t gm = (size_t)grp * LL;
    const size_t kvsz = (size_t)grp * NH * HD * DSTATE;

    unsigned short* P  = (unsigned short*)d_ws;             // gm*PSTRIDE fp16
    unsigned short* XC = P + gm * PSTRIDE;                  // gm*896 fp16
    float* KVpart = (float*)(XC + gm * CDIM);               // NCHUNK*kvsz f32
    unsigned short* KV16 = (unsigned short*)(KVpart + (size_t)NCHUNK * kvsz);
    unsigned short* u16  = KV16 + kvsz;                     // M*384
    unsigned short* Wi16 = u16 + (size_t)M * DMODEL;        // 1676*384
    unsigned short* Wo16 = Wi16 + (size_t)DPROJ * DMODEL;   // 384*768
    unsigned short* wt16 = Wo16 + (size_t)DMODEL * DINNER;  // 9*896

    // one-time fp16 converts / packs
    cvt_f16<<<((size_t)M * DMODEL / 4 + 255) / 256, 256, 0, stream>>>(u, u16, M * DMODEL / 4);
    cvt_f16<<<(DPROJ * DMODEL / 4 + 255) / 256, 256, 0, stream>>>(W_in, Wi16, DPROJ * DMODEL / 4);
    cvt_f16<<<(DMODEL * DINNER / 4 + 255) / 256, 256, 0, stream>>>(W_out, Wo16, DMODEL * DINNER / 4);
    pack_w16<<<(CDIM + 255) / 256, 256, 0, stream>>>(conv_w, wt16);

    const int nkv4 = (int)(kvsz / 4);

    for (int b0 = 0; b0 < B; b0 += grp) {
        // 1) P = u_grp @ W_in^T  (fp16 MFMA, fp16 store; grid %8==0, XCD-swizzled)
        gemm_h<4, 1><<<dim3(14, gm / 128), 256, 0, stream>>>(
            u16 + (size_t)b0 * LL * DMODEL, DMODEL, Wi16, DMODEL, P, PSTRIDE, DPROJ, DMODEL);

        // 2) depthwise conv + SiLU (packed fp16 math; grid %8==0, XCD-swizzled)
        conv_silu<<<dim3(LL / 4, grp), 128, 0, stream>>>(P, wt16, conv_b, XC);

        // 3) KV partials via MFMA (transposed fp16 staging, cf folded into B)
        kv_kernel<<<dim3(NH, grp, NCHUNK), 256, 0, stream>>>(XC, P, dt_bias, A_log, KVpart);

        // 4) reduce partials -> fp16 KV16
        kv_reduce<<<(nkv4 + 255) / 256, 256, 0, stream>>>(KVpart, KV16, nkv4);

        // 5) fused yg = (C@KV + x*D)*silu(z) + LayerNorm -> y fp16 into P z cols (LDS-staged)
        ckv_ln<<<dim3(LL / 16, grp), 256, 0, stream>>>(P, XC, KV16, Dp, ln_g, ln_b);

        // 6) out_grp = y @ W_out^T  (fp16 A in P, fp32 out; grid %8==0, swizzled)
        gemm_h<2, 0><<<dim3(3, gm / 64), 256, 0, stream>>>(
            P, PSTRIDE, Wo16, DINNER,
            out + (size_t)b0 * LL * DMODEL, DMODEL, DMODEL, DINNER);
    }
}